// Round 5
// baseline (553.146 us; speedup 1.0000x reference)
//
#include <hip/hip_runtime.h>
#include <hip/hip_bf16.h>

#define S_TOK 8192
#define DM    2048
#define DFF   8192
#define NE    8
#define CAP   1024

typedef __bf16 bf16_t;
typedef __bf16 bf16x8 __attribute__((ext_vector_type(8)));
typedef float  f32x4  __attribute__((ext_vector_type(4)));

__device__ __forceinline__ void load_lds16(const void* g, void* l) {
    __builtin_amdgcn_global_load_lds((const __attribute__((address_space(1))) void*)g,
                                     (__attribute__((address_space(3))) void*)l,
                                     16, 0, 0);
}

// ---------------- Kernel 1: gate logits + argmax — one wave per token ---------------
__global__ __launch_bounds__(256) void gate_argmax(const float* __restrict__ x,
                                                   const float* __restrict__ wg,
                                                   int* __restrict__ eidx) {
    int lane = threadIdx.x & 63, wv = threadIdx.x >> 6;
    int s = blockIdx.x * 4 + wv;
    const float* row = x + (size_t)s * DM;
    float acc[8] = {0.f,0.f,0.f,0.f,0.f,0.f,0.f,0.f};
    for (int kb = 0; kb < DM; kb += 256) {
        int k0 = kb + lane * 4;
        float4 xv = *(const float4*)(row + k0);
        const float* wr = wg + (size_t)k0 * NE;
        float xs[4] = {xv.x, xv.y, xv.z, xv.w};
#pragma unroll
        for (int c = 0; c < 4; ++c) {
            float4 w0 = *(const float4*)(wr + c * 8);
            float4 w1 = *(const float4*)(wr + c * 8 + 4);
            acc[0] += xs[c] * w0.x; acc[1] += xs[c] * w0.y;
            acc[2] += xs[c] * w0.z; acc[3] += xs[c] * w0.w;
            acc[4] += xs[c] * w1.x; acc[5] += xs[c] * w1.y;
            acc[6] += xs[c] * w1.z; acc[7] += xs[c] * w1.w;
        }
    }
#pragma unroll
    for (int off = 32; off > 0; off >>= 1)
#pragma unroll
        for (int e = 0; e < 8; ++e) acc[e] += __shfl_xor(acc[e], off, 64);
    if (lane == 0) {
        float best = acc[0]; int bi = 0;
#pragma unroll
        for (int e = 1; e < 8; ++e) if (acc[e] > best) { best = acc[e]; bi = e; }
        eidx[s] = bi;
    }
}

// ---------------- Kernel 2: slot assignment — single wave, prefetch-pipelined -------
__global__ __launch_bounds__(64) void scatter_slots(const int* __restrict__ eidx,
                                                    int* __restrict__ srcOf) {
    int lane = threadIdx.x;
    unsigned long long below = (lane == 0) ? 0ull : ((1ull << lane) - 1ull);
    for (int i = lane; i < NE * CAP; i += 64) srcOf[i] = -1;

    int cnt[NE] = {0,0,0,0,0,0,0,0};
    int e_cur = eidx[lane];
    for (int it = 0; it < S_TOK / 64; ++it) {
        int e_nxt = (it < S_TOK / 64 - 1) ? eidx[(it + 1) * 64 + lane] : 0;
        int s = it * 64 + lane;
#pragma unroll
        for (int ex = 0; ex < NE; ++ex) {
            unsigned long long m = __ballot(e_cur == ex);
            if (e_cur == ex) {
                int loc = cnt[ex] + __popcll(m & below);
                if (loc < CAP) srcOf[ex * CAP + loc] = s;
            }
            cnt[ex] += __popcll(m);
        }
        e_cur = e_nxt;
    }
}

// ---------------- Kernel 3: gather + f32->bf16 into PRE-SWIZZLED tile images --------
// abuf: per (e, mt, kt) a 32 KiB image of [256 m][64 k] bf16, row stride 128 B,
// byte addr within image = m*128 + ((kbyte) ^ ((m&7)<<4)).  gload_lds copies linearly.
__global__ __launch_bounds__(256) void pack_rows(const float* __restrict__ x,
                                                 const int* __restrict__ srcOf,
                                                 char* __restrict__ abuf) {
    int slot = blockIdx.x;               // e*1024 + c
    int e = slot >> 10, c = slot & 1023;
    int mt = c >> 8, m = c & 255;
    int src = srcOf[slot];
    int tid = threadIdx.x;
    int kt = tid >> 3, kg = tid & 7;     // kt 0..31, kg 0..7 (8 bf16 per 16 B)
    bf16x8 v = {};
    if (src >= 0) {
        const float4* p = (const float4*)(x + (size_t)src * DM + kt * 64 + kg * 8);
        float4 a = p[0], b = p[1];
        v = bf16x8{(bf16_t)a.x,(bf16_t)a.y,(bf16_t)a.z,(bf16_t)a.w,
                   (bf16_t)b.x,(bf16_t)b.y,(bf16_t)b.z,(bf16_t)b.w};
    }
    size_t img = ((size_t)((e * 4 + mt) * 32 + kt)) << 15;
    int off = m * 128 + ((kg * 16) ^ ((m & 7) << 4));
    *(bf16x8*)(abuf + img + off) = v;
}

// ---------------- Kernel 4: 256x256x64 bf16 MFMA GEMM, 8-phase schedule -------------
#define CLUSTER(MH, NH)                                                              \
    __builtin_amdgcn_s_setprio(1);                                                   \
    _Pragma("unroll")                                                                \
    for (int mf = 0; mf < 4; ++mf)                                                   \
        _Pragma("unroll")                                                            \
        for (int nf = 0; nf < 2; ++nf)                                               \
            _Pragma("unroll")                                                        \
            for (int kk = 0; kk < 2; ++kk)                                           \
                acc[(MH)*4 + mf][(NH)*2 + nf] =                                      \
                    __builtin_amdgcn_mfma_f32_16x16x32_bf16(                         \
                        af[mf][kk], bfA[NH][nf][kk],                                 \
                        acc[(MH)*4 + mf][(NH)*2 + nf], 0, 0, 0);                     \
    __builtin_amdgcn_s_setprio(0);

#define WAIT_LGKM0_SB()                                                              \
    asm volatile("s_waitcnt lgkmcnt(0)" ::: "memory");                               \
    __builtin_amdgcn_sched_barrier(0);

__global__ __launch_bounds__(512, 2) void moe_gemm(const char* __restrict__ abuf,
                                                   const float* __restrict__ we,
                                                   const float* __restrict__ be,
                                                   float* __restrict__ out) {
    __shared__ uint4 smem4[131072 / 16];           // [buf][A 32K | B 32K]
    char* smem = (char*)smem4;

    int bid = blockIdx.x;
    int e  = bid & 7;                   // expert == XCD
    int r  = bid >> 3;
    int mt = r & 3;
    int nt = r >> 2;
    int tid = threadIdx.x, lane = tid & 63, wv = tid >> 6;
    int wm = wv >> 2, wn = wv & 3;      // 2x4 wave grid -> 128x64 per wave
    int lr = lane & 15, g = lane >> 4;

    const char* aImg = abuf + (((size_t)((e * 4 + mt) * 32)) << 15);
    const float* bBase = we + (size_t)e * DM * DFF + (size_t)nt * 256 + lane * 4;
    int stOff = tid * 16;

    f32x4 acc[8][4] = {};
    float bs0[16], bs1[16];
    bf16x8 af[4][2];                    // [mf][kk]  (current mh half)
    bf16x8 bfA[2][2][2];                // [nh][nf][kk] held across the K-tile

    auto issueA = [&](int kt, int buf) {
        const char* src = aImg + ((size_t)kt << 15) + stOff;
        char* dst = smem + buf * 65536 + stOff;
#pragma unroll
        for (int i = 0; i < 4; ++i) load_lds16(src + i * 8192, dst + i * 8192);
    };
    auto issueB0 = [&](int kt) {
        const float* bp = bBase + (size_t)(kt * 64 + wv * 8) * DFF;
#pragma unroll
        for (int j = 0; j < 4; ++j) {
            float4 t = *(const float4*)(bp + (size_t)j * DFF);
            bs0[j*4+0] = t.x; bs0[j*4+1] = t.y; bs0[j*4+2] = t.z; bs0[j*4+3] = t.w;
        }
    };
    auto issueB1 = [&](int kt) {
        const float* bp = bBase + (size_t)(kt * 64 + wv * 8 + 4) * DFF;
#pragma unroll
        for (int j = 0; j < 4; ++j) {
            float4 t = *(const float4*)(bp + (size_t)j * DFF);
            bs1[j*4+0] = t.x; bs1[j*4+1] = t.y; bs1[j*4+2] = t.z; bs1[j*4+3] = t.w;
        }
    };
    auto writeB = [&](int buf, const float* bsv, int h) {
        char* bL = smem + buf * 65536 + 32768;
#pragma unroll
        for (int i = 0; i < 4; ++i) {
            int n = lane * 4 + i;
            ushort w[4];
#pragma unroll
            for (int j = 0; j < 4; ++j) {
                bf16_t b = (bf16_t)bsv[j * 4 + i];
                w[j] = __builtin_bit_cast(unsigned short, b);
            }
            uint2 pk = { (unsigned)w[0] | ((unsigned)w[1] << 16),
                         (unsigned)w[2] | ((unsigned)w[3] << 16) };
            int slot = (n & 7) ^ ((n >> 3) & 7);
            *(uint2*)(bL + n * 128 + (((unsigned)(wv ^ slot)) << 4) + h * 8) = pk;
        }
    };

    // prologue: tile 0 into buf 0 (full drain via __syncthreads)
    issueA(0, 0);
    issueB0(0);
    issueB1(0);
    writeB(0, bs0, 0);
    writeB(0, bs1, 1);
    __syncthreads();

    int aRowB = (wm * 128 + lr) * 128;
    int colA[2] = { ((0 * 4 + g) ^ (lr & 7)) << 4, ((1 * 4 + g) ^ (lr & 7)) << 4 };

    for (int kt = 0; kt < 32; ++kt) {
        int cur = kt & 1, nxt = cur ^ 1;
        bool nl = (kt < 31);
        const char* aC = smem + cur * 65536;
        const char* bC = aC + 32768;

        // ---- Phase 1: af(mh0) + bfr(nh0) reads; issue A-gload(kt+1) + B half0 ----
#pragma unroll
        for (int mf = 0; mf < 4; ++mf) {
            af[mf][0] = *(const bf16x8*)(aC + aRowB + mf * 2048 + colA[0]);
            af[mf][1] = *(const bf16x8*)(aC + aRowB + mf * 2048 + colA[1]);
        }
#pragma unroll
        for (int nf = 0; nf < 2; ++nf) {
            int rowB = wn * 64 + nf * 16 + lr;
            int xb = (lr & 7) ^ ((nf * 2 + (lr >> 3)) & 7);
#pragma unroll
            for (int kk = 0; kk < 2; ++kk)
                bfA[0][nf][kk] = *(const bf16x8*)(bC + rowB * 128 + (((kk * 4 + g) ^ xb) << 4));
        }
        if (nl) { issueA(kt + 1, nxt); issueB0(kt + 1); }
        __builtin_amdgcn_s_barrier();
        WAIT_LGKM0_SB();
        CLUSTER(0, 0);
        __builtin_amdgcn_s_barrier();

        // ---- Phase 2: bfr(nh1) reads; issue B half1 ----
#pragma unroll
        for (int nf = 0; nf < 2; ++nf) {
            int rowB = wn * 64 + 32 + nf * 16 + lr;
            int xb = (lr & 7) ^ ((4 + nf * 2 + (lr >> 3)) & 7);
#pragma unroll
            for (int kk = 0; kk < 2; ++kk)
                bfA[1][nf][kk] = *(const bf16x8*)(bC + rowB * 128 + (((kk * 4 + g) ^ xb) << 4));
        }
        if (nl) issueB1(kt + 1);
        __builtin_amdgcn_s_barrier();
        WAIT_LGKM0_SB();
        CLUSTER(0, 1);
        __builtin_amdgcn_s_barrier();

        // ---- Phase 3: af(mh1) reads ----
#pragma unroll
        for (int mf = 0; mf < 4; ++mf) {
            af[mf][0] = *(const bf16x8*)(aC + aRowB + 8192 + mf * 2048 + colA[0]);
            af[mf][1] = *(const bf16x8*)(aC + aRowB + 8192 + mf * 2048 + colA[1]);
        }
        __builtin_amdgcn_s_barrier();
        WAIT_LGKM0_SB();
        CLUSTER(1, 0);
        __builtin_amdgcn_s_barrier();

        // ---- Phase 4: writeB h0 (forces FIFO vmcnt past A-gloads); MFMA; writeB h1 ----
        if (nl) writeB(nxt, bs0, 0);
        __builtin_amdgcn_s_barrier();
        WAIT_LGKM0_SB();
        CLUSTER(1, 1);
        if (nl) writeB(nxt, bs1, 1);
        asm volatile("s_waitcnt lgkmcnt(0)" ::: "memory");   // publish ds_writes
        __builtin_amdgcn_s_barrier();                        // end of K-tile
    }

    // epilogue: C/D layout col=lane&15, row=(lane>>4)*4+q
    int orow0 = e * CAP + mt * 256 + wm * 128 + g * 4;
    int ocol0 = nt * 256 + wn * 64 + lr;
#pragma unroll
    for (int nf = 0; nf < 4; ++nf) {
        int oc = ocol0 + nf * 16;
        float bias = be[(size_t)e * DFF + oc];
#pragma unroll
        for (int mf = 0; mf < 8; ++mf) {
            int orow = orow0 + mf * 16;
#pragma unroll
            for (int q = 0; q < 4; ++q)
                out[(size_t)(orow + q) * DFF + oc] = acc[mf][nf][q] + bias;
        }
    }
}

// ---------------- launcher ----------------------------------------------------------
extern "C" void kernel_launch(void* const* d_in, const int* in_sizes, int n_in,
                              void* d_out, int out_size, void* d_ws, size_t ws_size,
                              hipStream_t stream) {
    const float* x  = (const float*)d_in[0];
    const float* wg = (const float*)d_in[1];
    const float* we = (const float*)d_in[2];
    const float* be = (const float*)d_in[3];
    float* out = (float*)d_out;

    size_t need = 65536 + (size_t)8 * 4 * 32 * 32768;   // 64 KB + 32 MB
    if (ws_size < need) return;

    int* eidx  = (int*)d_ws;
    int* srcOf = eidx + S_TOK;
    char* abuf = (char*)d_ws + 65536;

    gate_argmax<<<S_TOK / 4, 256, 0, stream>>>(x, wg, eidx);
    scatter_slots<<<1, 64, 0, stream>>>(eidx, srcOf);
    pack_rows<<<S_TOK, 256, 0, stream>>>(x, srcOf, abuf);
    moe_gemm<<<NE * 4 * 32, 512, 0, stream>>>(abuf, we, be, out);
}